// Round 10
// baseline (243.023 us; speedup 1.0000x reference)
//
#include <hip/hip_runtime.h>
#include <cstddef>

#define NH   8
#define NB   4
#define HD   32
#define NPIX 4096
#define NBATCH 8
#define NL   300
#define D    256
#define NQ   (NBATCH * NL)          // 2400

typedef __attribute__((ext_vector_type(4))) float  f32x4;
typedef __attribute__((ext_vector_type(8))) short  bf16x8;

__device__ __forceinline__ unsigned short f2bf(float f) {
    union { float f; unsigned u; } v; v.f = f;
    unsigned r = v.u + 0x7fffu + ((v.u >> 16) & 1u);   // round-to-nearest-even
    return (unsigned short)(r >> 16);
}
__device__ __forceinline__ float bf2f(unsigned short u) {
    union { unsigned u; float f; } v; v.u = ((unsigned)u) << 16; return v.f;
}
__device__ __forceinline__ unsigned cvtpk(float lo, float hi) {
    unsigned r;
    asm("v_cvt_pk_bf16_f32 %0, %1, %2" : "=v"(r) : "v"(lo), "v"(hi));
    return r;
}
__device__ __forceinline__ bf16x8 pack8c(f32x4 a, f32x4 b) {
    union { unsigned u[4]; bf16x8 v; } r;
    r.u[0] = cvtpk(a[0], a[1]); r.u[1] = cvtpk(a[2], a[3]);
    r.u[2] = cvtpk(b[0], b[1]); r.u[3] = cvtpk(b[2], b[3]);
    return r.v;
}

// ---------------- Kernel 1: vproj MFMA, BM=64/BN=256/BK=64, 512 thr, reg-prefetch -------
// M=32768 value rows, N=256 out dims, K=256. value read ONCE (full-width N).
// Prefetch next K-step's A/B into registers during current MFMAs (T14).
__global__ __launch_bounds__(512, 4)      // cap VGPR<=128 -> 2 blocks/CU co-resident
void vproj_kernel(const float* __restrict__ value, const float* __restrict__ Wvf,
                  const float* __restrict__ vbias, const unsigned char* __restrict__ mask,
                  unsigned short* __restrict__ vm)
{
    __shared__ __align__(16) short As[64][72];    // 9.2 KB
    __shared__ __align__(16) short Bs[256][72];   // 36.9 KB
    const int tid  = threadIdx.x;
    const int lane = tid & 63, wid = tid >> 6;    // 8 waves
    const int wm = wid >> 2, wn = wid & 3;        // 2x4 wave grid; wave tile 32(M)x64(N)
    const int row0 = blockIdx.x * 64;
    const int l16 = lane & 15, lg = lane >> 4;

    const int sr = tid >> 3, sc8 = (tid & 7) * 8; // staging: 8 thr/row, 32B chunks

    f32x4 acc[2][4] = {};
    f32x4 pA[2], pB[8];

    auto LOADK = [&](int k0) {
        const float* p = value + (size_t)(row0 + sr) * D + k0 + sc8;
        pA[0] = *(const f32x4*)p; pA[1] = *(const f32x4*)(p + 4);
        #pragma unroll
        for (int i = 0; i < 4; ++i) {
            const float* q = Wvf + (size_t)(sr + i * 64) * D + k0 + sc8;
            pB[2 * i] = *(const f32x4*)q; pB[2 * i + 1] = *(const f32x4*)(q + 4);
        }
    };

    LOADK(0);
    #pragma unroll
    for (int ks = 0; ks < 4; ++ks) {
        *(bf16x8*)&As[sr][sc8] = pack8c(pA[0], pA[1]);
        #pragma unroll
        for (int i = 0; i < 4; ++i)
            *(bf16x8*)&Bs[sr + i * 64][sc8] = pack8c(pB[2 * i], pB[2 * i + 1]);
        __syncthreads();
        if (ks < 3) LOADK((ks + 1) * 64);       // prefetch flies under MFMAs
        #pragma unroll
        for (int kk = 0; kk < 2; ++kk) {
            bf16x8 af[2], bfr[4];
            #pragma unroll
            for (int m = 0; m < 2; ++m)
                af[m] = *(const bf16x8*)&As[wm * 32 + m * 16 + l16][kk * 32 + lg * 8];
            #pragma unroll
            for (int n = 0; n < 4; ++n)
                bfr[n] = *(const bf16x8*)&Bs[wn * 64 + n * 16 + l16][kk * 32 + lg * 8];
            #pragma unroll
            for (int m = 0; m < 2; ++m)
                #pragma unroll
                for (int n = 0; n < 4; ++n)
                    acc[m][n] = __builtin_amdgcn_mfma_f32_16x16x32_bf16(af[m], bfr[n], acc[m][n], 0, 0, 0);
        }
        __syncthreads();
    }
    // epilogue: C/D col=lane&15, row=(lane>>4)*4+reg
    #pragma unroll
    for (int m = 0; m < 2; ++m) {
        #pragma unroll
        for (int r = 0; r < 4; ++r) {
            const int grow = row0 + wm * 32 + m * 16 + lg * 4 + r;
            const int bb = grow >> 12, pix = grow & (NPIX - 1);
            const float mf = (mask[grow] != 0) ? 0.f : 1.f;
            #pragma unroll
            for (int n = 0; n < 4; ++n) {
                const int gcol = wn * 64 + n * 16 + l16;
                const int h = gcol >> 5, dd = gcol & 31;
                vm[((size_t)(bb * NH + h) * NPIX + pix) * HD + dd] =
                    f2bf(mf * (acc[m][n][r] + vbias[gcol]));
            }
        }
    }
}

// ---------------- Kernel 2: box/attn f32 GEMM, 2400 x 256 x 256 -------------------------
__global__ __launch_bounds__(256)
void proj_kernel(const float* __restrict__ query,
                 const float* __restrict__ box_w, const float* __restrict__ box_b,
                 const float* __restrict__ attn_w, const float* __restrict__ attn_b,
                 float* __restrict__ bp, float* __restrict__ ap, float* __restrict__ awo)
{
    __shared__ float As[16][65];
    __shared__ float Bs[16][65];
    const int tid = threadIdx.x;
    const int tr = tid >> 4, tc = tid & 15;
    float acc[4][4] = {};
    const int row0 = blockIdx.x * 64, col0 = blockIdx.y * 64;
    for (int k0 = 0; k0 < D; k0 += 16) {
        #pragma unroll
        for (int i = 0; i < 4; ++i) {
            int idx = tid + i * 256;
            int r = idx >> 4, kk = idx & 15;
            int qrow = min(row0 + r, NQ - 1);
            As[kk][r] = query[(size_t)qrow * D + k0 + kk];
            int c256 = col0 + r;
            const float* src = (c256 < 128) ? (box_w + (size_t)c256 * D)
                                            : (attn_w + (size_t)(c256 - 128) * D);
            Bs[kk][r] = src[k0 + kk];
        }
        __syncthreads();
        #pragma unroll
        for (int kk = 0; kk < 16; ++kk) {
            float a[4], bv[4];
            #pragma unroll
            for (int i = 0; i < 4; ++i) a[i] = As[kk][tr * 4 + i];
            #pragma unroll
            for (int j = 0; j < 4; ++j) bv[j] = Bs[kk][tc * 4 + j];
            #pragma unroll
            for (int i = 0; i < 4; ++i)
                #pragma unroll
                for (int j = 0; j < 4; ++j)
                    acc[i][j] += a[i] * bv[j];
        }
        __syncthreads();
    }
    #pragma unroll
    for (int i = 0; i < 4; ++i) {
        int q = row0 + tr * 4 + i;
        if (q >= NQ) continue;
        #pragma unroll
        for (int j = 0; j < 4; ++j) {
            int col = col0 + tc * 4 + j;
            if (col < 128) {
                bp[(size_t)q * 128 + col] = acc[i][j] + box_b[col];
            } else {
                int rc = col - 128;
                float val = acc[i][j] + attn_b[rc];
                ap[(size_t)q * 128 + rc] = val;
                int h = rc >> 4, bx = (rc >> 2) & 3, rr = (rc >> 1) & 1, cc = rc & 1;
                float* awq = awo + (size_t)q * 512 + (size_t)(h * NB + bx) * 16;
                awq[(2 * rr + 0) * 4 + 2 * cc + 0] = val;
                awq[(2 * rr + 0) * 4 + 2 * cc + 1] = val;
                awq[(2 * rr + 1) * 4 + 2 * cc + 0] = val;
                awq[(2 * rr + 1) * 4 + 2 * cc + 1] = val;
            }
        }
    }
}

// ---------------- Kernel 3: sampling + FUSED oproj GEMV, XCD-affine ---------------------
// blockIdx swizzle: q = (bid&7)*300 + (bid>>3) -> all blocks of batch bb land on one XCD
// (bid%8 = XCD), so vm[bb] (2.1 MB bf16) stays resident in that XCD's 4 MB L2.
__global__ __launch_bounds__(256)
void sample_kernel(const unsigned short* __restrict__ vm, const float* __restrict__ bp,
                   const float* __restrict__ ap, const float* __restrict__ ref_windows,
                   const float* __restrict__ vratio, const int* __restrict__ vshape,
                   const float* __restrict__ oproj_w, const float* __restrict__ oproj_b,
                   float* __restrict__ out1, float* __restrict__ out2)
{
    __shared__ float sbp[128], sap[128], swh[128], lwh[128], sref4[4];
    __shared__ float4 boxdat[32];
    __shared__ int4   O4[512];
    __shared__ float4 W4[512];
    __shared__ float2 SL[512];
    __shared__ __align__(16) float r1s[256], r2s[256];
    const int bid = blockIdx.x, tid = threadIdx.x;
    const int blk = (bid & 7) * NL + (bid >> 3);     // XCD-affine query index
    const int bb = blk / NL;
    if (tid < 128) { sbp[tid] = bp[(size_t)blk * 128 + tid]; sap[tid] = ap[(size_t)blk * 128 + tid]; }
    if (tid < 4) sref4[tid] = ref_windows[(size_t)blk * 4 + tid];
    __syncthreads();
    const int Hf = vshape[0], Wf = vshape[1];
    const float Hff = (float)Hf, Wff = (float)Wf;
    const float vr0 = vratio[bb * 2 + 0], vr1 = vratio[bb * 2 + 1];

    if (tid < 128) {            // softmax over the 16 logits of head = tid>>4
        float a = sap[tid];     // lane k = box*4 + kpos
        float m = a;
        m = fmaxf(m, __shfl_xor(m, 1));
        m = fmaxf(m, __shfl_xor(m, 2));
        m = fmaxf(m, __shfl_xor(m, 4));
        m = fmaxf(m, __shfl_xor(m, 8));
        float e = expf(a - m);
        float ldv = e + __shfl_xor(e, 4);    // sum over boxes
        ldv += __shfl_xor(ldv, 8);
        float ss = ldv + __shfl_xor(ldv, 1); // sum over kpos -> total
        ss += __shfl_xor(ss, 2);
        swh[tid] = e / (4.f * ss);           // spatial weight
        lwh[tid] = e / ldv;                  // level weight
    } else if (tid < 160) {     // box geometry: j = h*4+box
        int j = tid - 128;
        float o0 = sbp[j * 4 + 0], o1 = sbp[j * 4 + 1];
        float o2 = sbp[j * 4 + 2], o3 = sbp[j * 4 + 3];
        float cx = sref4[0] + o0 * 0.125f * sref4[2];
        float cy = sref4[1] + o1 * 0.125f * sref4[3];
        float rw = fmaxf(sref4[2] + o2 * 0.125f * sref4[2], 0.f);
        float rh = fmaxf(sref4[3] + o3 * 0.125f * sref4[3], 0.f);
        boxdat[j] = make_float4(cx, cy, rw, rh);
    }
    __syncthreads();

    const float kidx[4] = {-0.375f, -0.125f, 0.125f, 0.375f};
    #pragma unroll
    for (int pp = 0; pp < 2; ++pp) {        // p = h*64 + box*16 + ii*4 + jj
        const int p = tid + pp * 256;
        const float4 bd = boxdat[p >> 4];
        const int ii = (p >> 2) & 3, jj = p & 3;
        const float gy = (bd.y + kidx[ii] * bd.w) * vr1;
        const float gx = (bd.x + kidx[jj] * bd.z) * vr0;
        const float y = gy * Hff - 0.5f, x = gx * Wff - 0.5f;
        const float y0f = floorf(y), x0f = floorf(x);
        const int iy0 = (int)y0f, ix0 = (int)x0f;
        const float wy1 = y - y0f, wx1 = x - x0f;
        const float wy0 = 1.f - wy1, wx0 = 1.f - wx1;
        const bool y0in = (iy0 >= 0) & (iy0 < Hf);
        const bool y1in = (iy0 + 1 >= 0) & (iy0 + 1 < Hf);
        const bool x0in = (ix0 >= 0) & (ix0 < Wf);
        const bool x1in = (ix0 + 1 >= 0) & (ix0 + 1 < Wf);
        const int yc0 = min(max(iy0, 0), Hf - 1), yc1 = min(max(iy0 + 1, 0), Hf - 1);
        const int xc0 = min(max(ix0, 0), Wf - 1), xc1 = min(max(ix0 + 1, 0), Wf - 1);
        O4[p] = make_int4((yc0 * Wf + xc0) * HD, (yc0 * Wf + xc1) * HD,
                          (yc1 * Wf + xc0) * HD, (yc1 * Wf + xc1) * HD);
        W4[p] = make_float4((y0in & x0in) ? wy0 * wx0 : 0.f,
                            (y0in & x1in) ? wy0 * wx1 : 0.f,
                            (y1in & x0in) ? wy1 * wx0 : 0.f,
                            (y1in & x1in) ? wy1 * wx1 : 0.f);
        // kpos = (ii>>1)*2 + (jj>>1) = bit3(p)<<1 | bit1(p)
        const int kpos = ((p >> 2) & 2) | ((p >> 1) & 1);
        const int hk = (p >> 6) * 16 + ((p >> 4) & 3) * 4 + kpos;
        SL[p] = make_float2(swh[hk], lwh[hk]);
    }
    __syncthreads();

    {
        const int h = tid >> 5, dd = tid & 31;
        const unsigned short* base = vm + ((size_t)(bb * NH + h) * NPIX) * HD + dd;
        float acc = 0.f, accm = 0.f;
        #pragma unroll 4
        for (int t = 0; t < 64; ++t) {
            const int p = h * 64 + t;
            const int4 o = O4[p]; const float4 w = W4[p]; const float2 sl = SL[p];
            const float samp = bf2f(base[o.x]) * w.x + bf2f(base[o.y]) * w.y
                             + bf2f(base[o.z]) * w.z + bf2f(base[o.w]) * w.w;
            acc  += samp * sl.x;
            accm += samp * sl.y;
        }
        r1s[tid] = acc;
        r2s[tid] = accm;
    }
    __syncthreads();

    // fused oproj GEMV (f32, exact): out[blk][tid] = b[tid] + sum_v r[v] * W[tid][v]
    float a1 = oproj_b[tid], a2 = a1;
    const float* wr = oproj_w + (size_t)tid * 256;
    #pragma unroll 8
    for (int v = 0; v < 256; v += 4) {
        const f32x4 wv = *(const f32x4*)(wr + v);
        const f32x4 x1 = *(const f32x4*)&r1s[v];   // LDS broadcast
        const f32x4 x2 = *(const f32x4*)&r2s[v];
        a1 += wv[0] * x1[0] + wv[1] * x1[1] + wv[2] * x1[2] + wv[3] * x1[3];
        a2 += wv[0] * x2[0] + wv[1] * x2[1] + wv[2] * x2[2] + wv[3] * x2[3];
    }
    out1[(size_t)blk * 256 + tid] = a1;
    out2[(size_t)blk * 256 + tid] = a2;
}

extern "C" void kernel_launch(void* const* d_in, const int* in_sizes, int n_in,
                              void* d_out, int out_size, void* d_ws, size_t ws_size,
                              hipStream_t stream)
{
    const float* query        = (const float*)d_in[0];
    const float* value        = (const float*)d_in[1];
    const int*   vshape       = (const int*)d_in[2];
    const unsigned char* vmask= (const unsigned char*)d_in[3];
    const float* vratio       = (const float*)d_in[5];
    const float* refw         = (const float*)d_in[6];
    const float* box_w        = (const float*)d_in[7];
    const float* box_b        = (const float*)d_in[8];
    const float* attn_w       = (const float*)d_in[9];
    const float* attn_b       = (const float*)d_in[10];
    const float* vproj_w      = (const float*)d_in[11];
    const float* vproj_b      = (const float*)d_in[12];
    const float* oproj_w      = (const float*)d_in[13];
    const float* oproj_b      = (const float*)d_in[14];

    unsigned short* vm_b = (unsigned short*)d_ws;      // 8,388,608 bf16 (16.8 MB)
    float* bp = (float*)(vm_b + 8388608);              // 307,200 f32
    float* ap = bp + 307200;                           // 307,200 f32

    float* out1 = (float*)d_out;          // output       614,400
    float* out2 = out1 + 614400;          // mask_output  614,400
    float* awo  = out2 + 614400;          // aw repeated  1,228,800

    vproj_kernel<<<512, 512, 0, stream>>>(value, vproj_w, vproj_b, vmask, vm_b);
    proj_kernel<<<dim3(38, 4), 256, 0, stream>>>(query, box_w, box_b, attn_w, attn_b, bp, ap, awo);
    sample_kernel<<<NQ, 256, 0, stream>>>(vm_b, bp, ap, refw, vratio, vshape,
                                          oproj_w, oproj_b, out1, out2);
}

// Round 11
// 209.975 us; speedup vs baseline: 1.1574x; 1.1574x over previous
//
#include <hip/hip_runtime.h>
#include <cstddef>

#define NH   8
#define NB   4
#define HD   32
#define NPIX 4096
#define NBATCH 8
#define NL   300
#define D    256
#define NQ   (NBATCH * NL)          // 2400

typedef __attribute__((ext_vector_type(4))) float  f32x4;
typedef __attribute__((ext_vector_type(8))) short  bf16x8;
typedef __attribute__((ext_vector_type(4))) unsigned short u16x4;

__device__ __forceinline__ unsigned short f2bf(float f) {
    union { float f; unsigned u; } v; v.f = f;
    unsigned r = v.u + 0x7fffu + ((v.u >> 16) & 1u);   // round-to-nearest-even
    return (unsigned short)(r >> 16);
}
__device__ __forceinline__ float bf2f(unsigned short u) {
    union { unsigned u; float f; } v; v.u = ((unsigned)u) << 16; return v.f;
}
__device__ __forceinline__ unsigned cvtpk(float lo, float hi) {
    unsigned r;
    asm("v_cvt_pk_bf16_f32 %0, %1, %2" : "=v"(r) : "v"(lo), "v"(hi));
    return r;
}
__device__ __forceinline__ bf16x8 pack8c(f32x4 a, f32x4 b) {
    union { unsigned u[4]; bf16x8 v; } r;
    r.u[0] = cvtpk(a[0], a[1]); r.u[1] = cvtpk(a[2], a[3]);
    r.u[2] = cvtpk(b[0], b[1]); r.u[3] = cvtpk(b[2], b[3]);
    return r.v;
}

// ---------------- Kernel 0: pack oproj_w -> transposed, v-quadded bf16 ------------------
// WTP[(v>>2)*1024 + j*4 + (v&3)] = bf16(W[j][v]); GEMV then reads 8B/lane coalesced.
__global__ __launch_bounds__(256)
void wpack_kernel(const float* __restrict__ W, unsigned short* __restrict__ WTP)
{
    const int g = blockIdx.x * 256 + threadIdx.x;   // 16384 threads
    const int j = g >> 6, v4 = g & 63;
    const f32x4 w = *(const f32x4*)(W + (size_t)j * 256 + v4 * 4);
    u16x4 o;
    o[0] = f2bf(w[0]); o[1] = f2bf(w[1]); o[2] = f2bf(w[2]); o[3] = f2bf(w[3]);
    *(u16x4*)(WTP + (size_t)v4 * 1024 + j * 4) = o;
}

// ---------------- Kernel 1: vproj MFMA, BM=64/BN=128/BK=64, 256 thr, 1024 blocks --------
// 4 blocks/CU co-resident (LDS 27.6KB, VGPR~120) + register prefetch of next K-step.
__global__ __launch_bounds__(256)
void vproj_kernel(const float* __restrict__ value, const float* __restrict__ Wvf,
                  const float* __restrict__ vbias, const unsigned char* __restrict__ mask,
                  unsigned short* __restrict__ vm)
{
    __shared__ __align__(16) short As[64][72];    // 9.2 KB
    __shared__ __align__(16) short Bs[128][72];   // 18.4 KB
    const int tid  = threadIdx.x;
    const int lane = tid & 63, wid = tid >> 6;    // 4 waves
    const int wm = wid >> 1, wn = wid & 1;        // 2x2 wave grid; wave tile 32(M)x64(N)
    const int mt = blockIdx.x >> 1, nt = blockIdx.x & 1;
    const int row0 = mt * 64, col0 = nt * 128;
    const int l16 = lane & 15, lg = lane >> 4;

    // staging: A row sr (4 thr/row, 64B each), B row br (2 thr/row, 128B each)
    const int sr = tid >> 2, sc = (tid & 3) * 16;
    const int br = tid >> 1, bc = (tid & 1) * 32;

    f32x4 acc[2][4] = {};
    f32x4 pA[4], pB[8];

    auto LOADK = [&](int k0) {
        const float* p = value + (size_t)(row0 + sr) * D + k0 + sc;
        pA[0] = *(const f32x4*)p;       pA[1] = *(const f32x4*)(p + 4);
        pA[2] = *(const f32x4*)(p + 8); pA[3] = *(const f32x4*)(p + 12);
        const float* q = Wvf + (size_t)(col0 + br) * D + k0 + bc;
        #pragma unroll
        for (int i = 0; i < 4; ++i) {
            pB[2 * i] = *(const f32x4*)(q + 8 * i);
            pB[2 * i + 1] = *(const f32x4*)(q + 8 * i + 4);
        }
    };

    LOADK(0);
    #pragma unroll
    for (int ks = 0; ks < 4; ++ks) {
        *(bf16x8*)&As[sr][sc]     = pack8c(pA[0], pA[1]);
        *(bf16x8*)&As[sr][sc + 8] = pack8c(pA[2], pA[3]);
        #pragma unroll
        for (int i = 0; i < 4; ++i)
            *(bf16x8*)&Bs[br][bc + 8 * i] = pack8c(pB[2 * i], pB[2 * i + 1]);
        __syncthreads();
        if (ks < 3) LOADK((ks + 1) * 64);       // prefetch flies under MFMAs
        #pragma unroll
        for (int kk = 0; kk < 2; ++kk) {
            bf16x8 af[2], bfr[4];
            #pragma unroll
            for (int m = 0; m < 2; ++m)
                af[m] = *(const bf16x8*)&As[wm * 32 + m * 16 + l16][kk * 32 + lg * 8];
            #pragma unroll
            for (int n = 0; n < 4; ++n)
                bfr[n] = *(const bf16x8*)&Bs[wn * 64 + n * 16 + l16][kk * 32 + lg * 8];
            #pragma unroll
            for (int m = 0; m < 2; ++m)
                #pragma unroll
                for (int n = 0; n < 4; ++n)
                    acc[m][n] = __builtin_amdgcn_mfma_f32_16x16x32_bf16(af[m], bfr[n], acc[m][n], 0, 0, 0);
        }
        __syncthreads();
    }
    // epilogue: C/D col=lane&15, row=(lane>>4)*4+reg
    #pragma unroll
    for (int m = 0; m < 2; ++m) {
        #pragma unroll
        for (int r = 0; r < 4; ++r) {
            const int grow = row0 + wm * 32 + m * 16 + lg * 4 + r;
            const int bb = grow >> 12, pix = grow & (NPIX - 1);
            const float mf = (mask[grow] != 0) ? 0.f : 1.f;
            #pragma unroll
            for (int n = 0; n < 4; ++n) {
                const int gcol = col0 + wn * 64 + n * 16 + l16;
                const int h = gcol >> 5, dd = gcol & 31;
                vm[((size_t)(bb * NH + h) * NPIX + pix) * HD + dd] =
                    f2bf(mf * (acc[m][n][r] + vbias[gcol]));
            }
        }
    }
}

// ---------------- Kernel 2: box/attn f32 GEMM, 2400 x 256 x 256 -------------------------
__global__ __launch_bounds__(256)
void proj_kernel(const float* __restrict__ query,
                 const float* __restrict__ box_w, const float* __restrict__ box_b,
                 const float* __restrict__ attn_w, const float* __restrict__ attn_b,
                 float* __restrict__ bp, float* __restrict__ ap, float* __restrict__ awo)
{
    __shared__ float As[16][65];
    __shared__ float Bs[16][65];
    const int tid = threadIdx.x;
    const int tr = tid >> 4, tc = tid & 15;
    float acc[4][4] = {};
    const int row0 = blockIdx.x * 64, col0 = blockIdx.y * 64;
    for (int k0 = 0; k0 < D; k0 += 16) {
        #pragma unroll
        for (int i = 0; i < 4; ++i) {
            int idx = tid + i * 256;
            int r = idx >> 4, kk = idx & 15;
            int qrow = min(row0 + r, NQ - 1);
            As[kk][r] = query[(size_t)qrow * D + k0 + kk];
            int c256 = col0 + r;
            const float* src = (c256 < 128) ? (box_w + (size_t)c256 * D)
                                            : (attn_w + (size_t)(c256 - 128) * D);
            Bs[kk][r] = src[k0 + kk];
        }
        __syncthreads();
        #pragma unroll
        for (int kk = 0; kk < 16; ++kk) {
            float a[4], bv[4];
            #pragma unroll
            for (int i = 0; i < 4; ++i) a[i] = As[kk][tr * 4 + i];
            #pragma unroll
            for (int j = 0; j < 4; ++j) bv[j] = Bs[kk][tc * 4 + j];
            #pragma unroll
            for (int i = 0; i < 4; ++i)
                #pragma unroll
                for (int j = 0; j < 4; ++j)
                    acc[i][j] += a[i] * bv[j];
        }
        __syncthreads();
    }
    #pragma unroll
    for (int i = 0; i < 4; ++i) {
        int q = row0 + tr * 4 + i;
        if (q >= NQ) continue;
        #pragma unroll
        for (int j = 0; j < 4; ++j) {
            int col = col0 + tc * 4 + j;
            if (col < 128) {
                bp[(size_t)q * 128 + col] = acc[i][j] + box_b[col];
            } else {
                int rc = col - 128;
                float val = acc[i][j] + attn_b[rc];
                ap[(size_t)q * 128 + rc] = val;
                int h = rc >> 4, bx = (rc >> 2) & 3, rr = (rc >> 1) & 1, cc = rc & 1;
                float* awq = awo + (size_t)q * 512 + (size_t)(h * NB + bx) * 16;
                awq[(2 * rr + 0) * 4 + 2 * cc + 0] = val;
                awq[(2 * rr + 0) * 4 + 2 * cc + 1] = val;
                awq[(2 * rr + 1) * 4 + 2 * cc + 0] = val;
                awq[(2 * rr + 1) * 4 + 2 * cc + 1] = val;
            }
        }
    }
}

// ---------------- Kernel 3: sampling + fused oproj GEMV (coalesced WTP), XCD-affine -----
__global__ __launch_bounds__(256)
void sample_kernel(const unsigned short* __restrict__ vm, const float* __restrict__ bp,
                   const float* __restrict__ ap, const float* __restrict__ ref_windows,
                   const float* __restrict__ vratio, const int* __restrict__ vshape,
                   const unsigned short* __restrict__ WTP, const float* __restrict__ oproj_b,
                   float* __restrict__ out1, float* __restrict__ out2)
{
    __shared__ float sbp[128], sap[128], swh[128], lwh[128], sref4[4];
    __shared__ float4 boxdat[32];
    __shared__ int4   O4[512];
    __shared__ float4 W4[512];
    __shared__ float2 SL[512];
    __shared__ __align__(16) float r1s[256], r2s[256];
    const int bid = blockIdx.x, tid = threadIdx.x;
    const int blk = (bid & 7) * NL + (bid >> 3);     // XCD-affine query index
    const int bb = blk / NL;
    if (tid < 128) { sbp[tid] = bp[(size_t)blk * 128 + tid]; sap[tid] = ap[(size_t)blk * 128 + tid]; }
    if (tid < 4) sref4[tid] = ref_windows[(size_t)blk * 4 + tid];
    __syncthreads();
    const int Hf = vshape[0], Wf = vshape[1];
    const float Hff = (float)Hf, Wff = (float)Wf;
    const float vr0 = vratio[bb * 2 + 0], vr1 = vratio[bb * 2 + 1];

    if (tid < 128) {            // softmax over the 16 logits of head = tid>>4
        float a = sap[tid];     // lane k = box*4 + kpos
        float m = a;
        m = fmaxf(m, __shfl_xor(m, 1));
        m = fmaxf(m, __shfl_xor(m, 2));
        m = fmaxf(m, __shfl_xor(m, 4));
        m = fmaxf(m, __shfl_xor(m, 8));
        float e = expf(a - m);
        float ldv = e + __shfl_xor(e, 4);    // sum over boxes
        ldv += __shfl_xor(ldv, 8);
        float ss = ldv + __shfl_xor(ldv, 1); // sum over kpos -> total
        ss += __shfl_xor(ss, 2);
        swh[tid] = e / (4.f * ss);           // spatial weight
        lwh[tid] = e / ldv;                  // level weight
    } else if (tid < 160) {     // box geometry: j = h*4+box
        int j = tid - 128;
        float o0 = sbp[j * 4 + 0], o1 = sbp[j * 4 + 1];
        float o2 = sbp[j * 4 + 2], o3 = sbp[j * 4 + 3];
        float cx = sref4[0] + o0 * 0.125f * sref4[2];
        float cy = sref4[1] + o1 * 0.125f * sref4[3];
        float rw = fmaxf(sref4[2] + o2 * 0.125f * sref4[2], 0.f);
        float rh = fmaxf(sref4[3] + o3 * 0.125f * sref4[3], 0.f);
        boxdat[j] = make_float4(cx, cy, rw, rh);
    }
    __syncthreads();

    const float kidx[4] = {-0.375f, -0.125f, 0.125f, 0.375f};
    #pragma unroll
    for (int pp = 0; pp < 2; ++pp) {        // p = h*64 + box*16 + ii*4 + jj
        const int p = tid + pp * 256;
        const float4 bd = boxdat[p >> 4];
        const int ii = (p >> 2) & 3, jj = p & 3;
        const float gy = (bd.y + kidx[ii] * bd.w) * vr1;
        const float gx = (bd.x + kidx[jj] * bd.z) * vr0;
        const float y = gy * Hff - 0.5f, x = gx * Wff - 0.5f;
        const float y0f = floorf(y), x0f = floorf(x);
        const int iy0 = (int)y0f, ix0 = (int)x0f;
        const float wy1 = y - y0f, wx1 = x - x0f;
        const float wy0 = 1.f - wy1, wx0 = 1.f - wx1;
        const bool y0in = (iy0 >= 0) & (iy0 < Hf);
        const bool y1in = (iy0 + 1 >= 0) & (iy0 + 1 < Hf);
        const bool x0in = (ix0 >= 0) & (ix0 < Wf);
        const bool x1in = (ix0 + 1 >= 0) & (ix0 + 1 < Wf);
        const int yc0 = min(max(iy0, 0), Hf - 1), yc1 = min(max(iy0 + 1, 0), Hf - 1);
        const int xc0 = min(max(ix0, 0), Wf - 1), xc1 = min(max(ix0 + 1, 0), Wf - 1);
        O4[p] = make_int4((yc0 * Wf + xc0) * HD, (yc0 * Wf + xc1) * HD,
                          (yc1 * Wf + xc0) * HD, (yc1 * Wf + xc1) * HD);
        W4[p] = make_float4((y0in & x0in) ? wy0 * wx0 : 0.f,
                            (y0in & x1in) ? wy0 * wx1 : 0.f,
                            (y1in & x0in) ? wy1 * wx0 : 0.f,
                            (y1in & x1in) ? wy1 * wx1 : 0.f);
        // kpos = (ii>>1)*2 + (jj>>1) = bit3(p)<<1 | bit1(p)
        const int kpos = ((p >> 2) & 2) | ((p >> 1) & 1);
        const int hk = (p >> 6) * 16 + ((p >> 4) & 3) * 4 + kpos;
        SL[p] = make_float2(swh[hk], lwh[hk]);
    }
    __syncthreads();

    {
        const int h = tid >> 5, dd = tid & 31;
        const unsigned short* base = vm + ((size_t)(bb * NH + h) * NPIX) * HD + dd;
        float acc = 0.f, accm = 0.f;
        #pragma unroll 4
        for (int t = 0; t < 64; ++t) {
            const int p = h * 64 + t;
            const int4 o = O4[p]; const float4 w = W4[p]; const float2 sl = SL[p];
            const float samp = bf2f(base[o.x]) * w.x + bf2f(base[o.y]) * w.y
                             + bf2f(base[o.z]) * w.z + bf2f(base[o.w]) * w.w;
            acc  += samp * sl.x;
            accm += samp * sl.y;
        }
        r1s[tid] = acc;
        r2s[tid] = accm;
    }
    __syncthreads();

    // fused oproj GEMV, coalesced: WTP[(v>>2)*1024 + tid*4 + (v&3)], 8B/lane loads
    float a1 = oproj_b[tid], a2 = a1;
    const unsigned short* wp = WTP + (size_t)tid * 4;
    #pragma unroll 8
    for (int v4 = 0; v4 < 64; ++v4) {
        const u16x4 wv = *(const u16x4*)(wp + v4 * 1024);
        const f32x4 x1 = *(const f32x4*)&r1s[v4 * 4];   // LDS broadcast
        const f32x4 x2 = *(const f32x4*)&r2s[v4 * 4];
        const float w0 = bf2f(wv[0]), w1 = bf2f(wv[1]), w2 = bf2f(wv[2]), w3 = bf2f(wv[3]);
        a1 += w0 * x1[0] + w1 * x1[1] + w2 * x1[2] + w3 * x1[3];
        a2 += w0 * x2[0] + w1 * x2[1] + w2 * x2[2] + w3 * x2[3];
    }
    out1[(size_t)blk * 256 + tid] = a1;
    out2[(size_t)blk * 256 + tid] = a2;
}

extern "C" void kernel_launch(void* const* d_in, const int* in_sizes, int n_in,
                              void* d_out, int out_size, void* d_ws, size_t ws_size,
                              hipStream_t stream)
{
    const float* query        = (const float*)d_in[0];
    const float* value        = (const float*)d_in[1];
    const int*   vshape       = (const int*)d_in[2];
    const unsigned char* vmask= (const unsigned char*)d_in[3];
    const float* vratio       = (const float*)d_in[5];
    const float* refw         = (const float*)d_in[6];
    const float* box_w        = (const float*)d_in[7];
    const float* box_b        = (const float*)d_in[8];
    const float* attn_w       = (const float*)d_in[9];
    const float* attn_b       = (const float*)d_in[10];
    const float* vproj_w      = (const float*)d_in[11];
    const float* vproj_b      = (const float*)d_in[12];
    const float* oproj_w      = (const float*)d_in[13];
    const float* oproj_b      = (const float*)d_in[14];

    unsigned short* vm_b = (unsigned short*)d_ws;      // 8,388,608 bf16 (16.8 MB)
    unsigned short* wtp  = vm_b + 8388608;             // 65,536 bf16 (packed W^T)
    float* bp = (float*)(wtp + 65536);                 // 307,200 f32
    float* ap = bp + 307200;                           // 307,200 f32

    float* out1 = (float*)d_out;          // output       614,400
    float* out2 = out1 + 614400;          // mask_output  614,400
    float* awo  = out2 + 614400;          // aw repeated  1,228,800

    wpack_kernel<<<64, 256, 0, stream>>>(oproj_w, wtp);
    vproj_kernel<<<1024, 256, 0, stream>>>(value, vproj_w, vproj_b, vmask, vm_b);
    proj_kernel<<<dim3(38, 4), 256, 0, stream>>>(query, box_w, box_b, attn_w, attn_b, bp, ap, awo);
    sample_kernel<<<NQ, 256, 0, stream>>>(vm_b, bp, ap, refw, vratio, vshape,
                                          wtp, oproj_b, out1, out2);
}